// Round 11
// baseline (165.773 us; speedup 1.0000x reference)
//
#include <hip/hip_runtime.h>
#include <stdint.h>

// Problem: BS=8, N=2048, D=512
// out[b,i,d] = sigmoid(q)[b,i,d] * (eB @ (ek*v)) / (eB @ ek)
#define N_SEQ 2048
#define D_MODEL 512
#define MROWS 16384   // BS*N
#define NT_K 32       // K-tiles (K=2048 / BK=64) in main GEMM

typedef __attribute__((ext_vector_type(8))) short bf16x8;
typedef __attribute__((ext_vector_type(4))) float f32x4;
typedef __attribute__((ext_vector_type(16))) float f32x16;

__device__ __forceinline__ short f2bf(float f) {
  union { float f; uint32_t u; } x; x.f = f;
  uint32_t r = x.u + 0x7FFFu + ((x.u >> 16) & 1u);
  return (short)(uint16_t)(r >> 16);
}
__device__ __forceinline__ unsigned short f2h(float f) {
  union { _Float16 h; unsigned short u; } x; x.h = (_Float16)f; return x.u;
}
__device__ __forceinline__ float h2f(unsigned short u) {
  union { unsigned short u; _Float16 h; } x; x.u = u; return (float)x.h;
}

__device__ __forceinline__ void gload_lds16(const void* g, void* l) {
  __builtin_amdgcn_global_load_lds(
      (__attribute__((address_space(1))) void*)(void*)g,
      (__attribute__((address_space(3))) void*)l, 16, 0, 0);
}

// ---------------- prep kernels ----------------

__global__ void k_conv_bf16(const float* __restrict__ in,
                            short* __restrict__ a, int n4) {
  int stride = gridDim.x * blockDim.x;
  for (int i = blockIdx.x * blockDim.x + threadIdx.x; i < n4; i += stride) {
    float4 v = reinterpret_cast<const float4*>(in)[i];
    short4 h;
    h.x = f2bf(v.x); h.y = f2bf(v.y); h.z = f2bf(v.z); h.w = f2bf(v.w);
    reinterpret_cast<short4*>(a)[i] = h;
  }
}

__global__ void k_prep_eb(const float* __restrict__ pb, short* __restrict__ eb,
                          int n4) {
  int stride = gridDim.x * blockDim.x;
  for (int i = blockIdx.x * blockDim.x + threadIdx.x; i < n4; i += stride) {
    float4 v = reinterpret_cast<const float4*>(pb)[i];
    short4 o;
    o.x = f2bf(expf(v.x));
    o.y = f2bf(expf(v.y));
    o.z = f2bf(expf(v.z));
    o.w = f2bf(expf(v.w));
    reinterpret_cast<short4*>(eb)[i] = o;
  }
}

// Wt[c][k] bf16, col-major over k.  c<512: Wq col c; c>=512: c=512+2d+s,
// s=0 -> Wk col d, s=1 -> Wv col d
__global__ void k_prep_w(const float* __restrict__ Wq, const float* __restrict__ Wk,
                         const float* __restrict__ Wv, short* __restrict__ wh) {
  int t = blockIdx.x * blockDim.x + threadIdx.x;
  if (t >= 1536 * 512) return;
  int c = t >> 9, k = t & 511;
  float v;
  if (c < 512) v = Wq[k * 512 + c];
  else {
    int cc = c - 512, d = cc >> 1;
    v = (cc & 1) ? Wv[k * 512 + d] : Wk[k * 512 + d];
  }
  wh[t] = f2bf(v);
}

// ---------------- projection GEMM (128^2 2-phase) ----------------
// Epilogue writes X in 32x32-B-frag layout Xf (kg16-major):
// element (col, j):  kg16=j>>4, ct32=col>>5, ln=(col&31)+32*((j>>3)&1),
// e=j&7  ->  Xf[(kg16<<17) + (ct32<<9) + (ln<<3) + e].
// A wave's B-frag (16k x 32col) for one kstep is then contiguous:
// base + lane*16B, with the n-frag offset (512 shorts) folding into the
// load immediate.  A and B both use klocal=(lane>>5)*8+e so any hardware
// k-permutation cancels between the operands.
__global__ __launch_bounds__(256) void k_proj(
    const short* __restrict__ A, const short* __restrict__ W,
    const float* __restrict__ bq, const float* __restrict__ bk,
    const float* __restrict__ bv,
    unsigned short* __restrict__ sigq, short* __restrict__ Xf) {
  __shared__ short lA[128 * 64], lB[128 * 64];
  const int tid = threadIdx.x;
  const int lane = tid & 63, wid = tid >> 6;
  const int wr = wid >> 1, wc = wid & 1;
  const int lrow = lane & 15;
  const int kq = (lane >> 4) << 4;
  const int row0 = blockIdx.x * 128;
  const int col0 = blockIdx.y * 128;

  const f32x4 fzero = {0.f, 0.f, 0.f, 0.f};
  f32x4 acc[4][4];
#pragma unroll
  for (int m = 0; m < 4; ++m)
#pragma unroll
    for (int n = 0; n < 4; ++n) acc[m][n] = fzero;

  const short* gA = A + row0 * 512;
  const short* gB = W + col0 * 512;

  for (int kt = 0; kt < 8; ++kt) {
    const int kb = kt * 64;
#pragma unroll
    for (int p = 0; p < 4; ++p) {
      int c = p * 256 + tid;
      int B = c << 4;
      int r = B >> 7;
      int wp = (B & 127) ^ ((r & 7) << 4);
      int ke = wp >> 1;
      int goff = r * 512 + kb + ke;
      int loff = (p * 256 + wid * 64) << 3;
      gload_lds16(gA + goff, lA + loff);
      gload_lds16(gB + goff, lB + loff);
    }
    __syncthreads();
#pragma unroll
    for (int ks = 0; ks < 2; ++ks) {
      int kb2 = kq + ks * 64;
      bf16x8 fb[4];
#pragma unroll
      for (int n = 0; n < 4; ++n) {
        int r = wc * 64 + n * 16 + lrow;
        fb[n] = *(const bf16x8*)((const char*)lB + (r << 7) +
                                 (kb2 ^ ((r & 7) << 4)));
      }
#pragma unroll
      for (int m = 0; m < 4; ++m) {
        int r = wr * 64 + m * 16 + lrow;
        bf16x8 fa = *(const bf16x8*)((const char*)lA + (r << 7) +
                                     (kb2 ^ ((r & 7) << 4)));
#pragma unroll
        for (int n = 0; n < 4; ++n)
          acc[m][n] = __builtin_amdgcn_mfma_f32_16x16x32_bf16(fa, fb[n], acc[m][n], 0, 0, 0);
      }
    }
    __syncthreads();
  }

  const int rbase = row0 + wr * 64 + ((lane >> 4) << 2);
  if (col0 < 512) {
#pragma unroll
    for (int n = 0; n < 4; ++n) {
      int c = col0 + wc * 64 + n * 16 + lrow;
      float bias = bq[c];
#pragma unroll
      for (int m = 0; m < 4; ++m) {
        int gr = rbase + m * 16;
#pragma unroll
        for (int r = 0; r < 4; ++r) {
          float q = acc[m][n][r] + bias;
          sigq[(gr + r) * 512 + c] = f2h(1.f / (1.f + expf(-q)));
        }
      }
    }
  } else {
    int s = lane & 1;
#pragma unroll
    for (int n = 0; n < 4; ++n) {
      int c = col0 + wc * 64 + n * 16 + lrow;
      int d = (c - 512) >> 1;
      float bias = s ? bv[d] : bk[d];
#pragma unroll
      for (int m = 0; m < 4; ++m) {
        int gr = rbase + m * 16;
        int b = gr >> 11;
        int j = gr & 2047;
        f32x4 val;
#pragma unroll
        for (int r = 0; r < 4; ++r) val[r] = acc[m][n][r] + bias;
        if (!s) {
#pragma unroll
          for (int r = 0; r < 4; ++r) val[r] = expf(val[r]);
        }
        f32x4 oth;
#pragma unroll
        for (int r = 0; r < 4; ++r) oth[r] = __shfl_xor(val[r], 1);
        if (!s) {
          short4 wq, eq;
          wq.x = f2bf(val[0] * oth[0]); eq.x = f2bf(val[0]);
          wq.y = f2bf(val[1] * oth[1]); eq.y = f2bf(val[1]);
          wq.z = f2bf(val[2] * oth[2]); eq.z = f2bf(val[2]);
          wq.w = f2bf(val[3] * oth[3]); eq.w = f2bf(val[3]);
          int colp = b * 1024 + 2 * d;  // num col; colp+1 = den col
          // 32x32 B-frag layout (kg16-major)
          int kg16 = j >> 4;
          int lnn = (colp & 31) + (((j >> 3) & 1) << 5);
          int e0 = j & 7;               // 0 or 4
          size_t base = ((size_t)kg16 << 17) + (((size_t)(colp >> 5)) << 9);
          *(short4*)&Xf[base + (lnn << 3) + e0] = wq;        // num col
          *(short4*)&Xf[base + ((lnn + 1) << 3) + e0] = eq;  // den col
        }
      }
    }
  }
}

// ---------------- main GEMM v8: 32x32x16 MFMA, R10 structure ---------------
// 256x128 tile, 512 thr = 8 waves (4M x 2N), 2 blocks/CU.
// Per-wave 64x64 out = 2x2 of 32x32 frags; acc = f32x16[2][2] (64 regs).
// A via LDS (2x32KB dbuf, XOR swizzle); B direct global->VGPR from kg16-major
// Xf (one per-thread offset VGPR).  Single fb[8] with WAR half-refill
// (half h = ksteps 2h,2h+1).  16 MFMA/K-tile/wave @ ~8cyc — half the
// instruction count of the 16x16 version at 17% less matrix-pipe time.
__global__ __launch_bounds__(512, 4) void k_main8(
    const short* __restrict__ eB, const short* __restrict__ Xf,
    const unsigned short* __restrict__ sigq, float* __restrict__ out) {
  extern __shared__ short lds[];  // 32768 shorts = 64 KB (2 bufs)
  const int tid = threadIdx.x;
  const int lane = tid & 63, wid = tid >> 6;
  const int wr = wid >> 1, wc = wid & 1;  // 4M x 2N
  const int l31 = lane & 31;
  const int lhi = lane >> 5;  // k-half select

  // XCD chunk swizzle: 512 blocks = 8 Mtiles x 64 Ntiles; xcd (=bid%8) gets
  // all 8 rows x 8 cols.
  const int bid = blockIdx.x;
  const int xcd = bid & 7, bj = bid >> 3;
  const int row0 = (bj & 7) * 256;
  const int col0 = ((xcd << 3) + (bj >> 3)) * 128;

  f32x16 acc[2][2];
#pragma unroll
  for (int m = 0; m < 2; ++m)
#pragma unroll
    for (int n = 0; n < 2; ++n)
#pragma unroll
      for (int r = 0; r < 16; ++r) acc[m][n][r] = 0.f;

  const short* gA = eB + row0 * 2048;
  // per-thread B offset (shorts): ct32*512 + lane*8, ct32 = col0/32 + wc*2
  const int pfo = ((col0 >> 5) + wc * 2) * 512 + (lane << 3);

  // stage A-tile kt (256 rows x 64 k = 32 KB) into buf kt&1: 4 chunks/thread
  auto STAGE = [&](int kt) {
    const short* src = gA + kt * 64;
    const int sb = (kt & 1) << 14;  // buf base in shorts
#pragma unroll
    for (int p = 0; p < 4; ++p) {
      int c = p * 512 + tid;
      int r = c >> 3;
      int ke = ((((c & 7) << 4) ^ (((c >> 3) & 7) << 4)) >> 1);
      gload_lds16(src + r * 2048 + ke,
                  lds + sb + ((p * 512 + wid * 64) << 3));
    }
  };
  // A-frag for (buf, kstep ks in 0..3, m in 0..1):
  // row R = wr*64 + m*32 + l31; klocal byte = ks*32 + lhi*16 (8 elems contig)
  auto LDA = [&](int b, int ks, int m) -> bf16x8 {
    int R = wr * 64 + m * 32 + l31;
    int kb = ks * 32 + (lhi << 4);
    return *(const bf16x8*)((const char*)lds + (b << 15) + R * 128 +
                            (kb ^ ((R & 7) << 4)));
  };
  // load 4 B-frags (half h: ksteps 2h,2h+1 x n 0..1) of K-tile kt
  auto LOADFB = [&](bf16x8* fb, int kt, int h) {
#pragma unroll
    for (int k2 = 0; k2 < 2; ++k2) {
      const short* base = Xf + (((size_t)(kt * 4 + h * 2 + k2)) << 17) + pfo;
      fb[k2 * 2 + 0] = *(const bf16x8*)(base);
      fb[k2 * 2 + 1] = *(const bf16x8*)(base + 512);
    }
  };

  bf16x8 fb[8];

  // prologue: A tile0 -> buf0, B tile0 -> fb
  STAGE(0);
  LOADFB(fb, 0, 0);
  LOADFB(fb + 4, 0, 1);
  __syncthreads();  // full drain: buf0 + fb ready

  for (int t = 0; t < NT_K; ++t) {
    const int b = t & 1;
    if (t + 1 < NT_K) STAGE(t + 1);
    // half0: ksteps 0,1 with fb[0..3], then refill for tile t+1
    {
      bf16x8 fa[4];
#pragma unroll
      for (int k2 = 0; k2 < 2; ++k2)
#pragma unroll
        for (int m = 0; m < 2; ++m) fa[k2 * 2 + m] = LDA(b, k2, m);
      __builtin_amdgcn_s_setprio(1);
#pragma unroll
      for (int k2 = 0; k2 < 2; ++k2)
#pragma unroll
        for (int m = 0; m < 2; ++m)
#pragma unroll
          for (int n = 0; n < 2; ++n)
            acc[m][n] = __builtin_amdgcn_mfma_f32_32x32x16_bf16(
                fa[k2 * 2 + m], fb[k2 * 2 + n], acc[m][n], 0, 0, 0);
      __builtin_amdgcn_s_setprio(0);
    }
    if (t + 1 < NT_K) LOADFB(fb, t + 1, 0);
    // half1: ksteps 2,3 with fb[4..7], then refill for tile t+1
    {
      bf16x8 fa[4];
#pragma unroll
      for (int k2 = 0; k2 < 2; ++k2)
#pragma unroll
        for (int m = 0; m < 2; ++m) fa[k2 * 2 + m] = LDA(b, 2 + k2, m);
      __builtin_amdgcn_s_setprio(1);
#pragma unroll
      for (int k2 = 0; k2 < 2; ++k2)
#pragma unroll
        for (int m = 0; m < 2; ++m)
#pragma unroll
          for (int n = 0; n < 2; ++n)
            acc[m][n] = __builtin_amdgcn_mfma_f32_32x32x16_bf16(
                fa[k2 * 2 + m], fb[4 + k2 * 2 + n], acc[m][n], 0, 0, 0);
      __builtin_amdgcn_s_setprio(0);
    }
    if (t + 1 < NT_K) LOADFB(fb + 4, t + 1, 1);
    __syncthreads();  // drains STAGE+LOADFB (covered by ks-MFMAs); swap bufs
  }

  // epilogue: 32x32 C/D frag: col = lane&31, row = (r&3) + 8*(r>>2) + 4*lhi
  const int rb32 = row0 + wr * 64 + (lhi << 2);
#pragma unroll
  for (int n = 0; n < 2; ++n) {
    int c = col0 + wc * 64 + n * 32 + l31;
    int b = c >> 10;
    int d = (c & 1023) >> 1;
#pragma unroll
    for (int m = 0; m < 2; ++m) {
      f32x16 den;
#pragma unroll
      for (int r = 0; r < 16; ++r) den[r] = __shfl_xor(acc[m][n][r], 1);
      if ((lane & 1) == 0) {  // even lane: acc=num, partner holds den
#pragma unroll
        for (int r = 0; r < 16; ++r) {
          int i2 = rb32 + m * 32 + (r & 3) + ((r >> 2) << 3);
          int idx = (b * 2048 + i2) * 512 + d;
          out[idx] = h2f(sigq[idx]) * (acc[m][n][r] / den[r]);
        }
      }
    }
  }
}

// ---------------- launch ----------------
extern "C" void kernel_launch(void* const* d_in, const int* in_sizes, int n_in,
                              void* d_out, int out_size, void* d_ws, size_t ws_size,
                              hipStream_t stream) {
  const float* in = (const float*)d_in[0];
  const float* Wq = (const float*)d_in[1];
  const float* bq = (const float*)d_in[2];
  const float* Wk = (const float*)d_in[3];
  const float* bk = (const float*)d_in[4];
  const float* Wv = (const float*)d_in[5];
  const float* bv = (const float*)d_in[6];
  const float* pb = (const float*)d_in[7];
  float* out = (float*)d_out;

  char* ws = (char*)d_ws;
  short* Xf = (short*)ws;                              // 33,554,432 B
  short* eB = (short*)(ws + 33554432);                 //  8,388,608 B
  short* Ah = (short*)(ws + 41943040);                 // 16,777,216 B
  short* Wh = (short*)(ws + 58720256);                 //  1,572,864 B
  unsigned short* sigq = (unsigned short*)(ws + 60293120);  // 16,777,216 B

  (void)hipFuncSetAttribute((const void*)k_main8,
                            hipFuncAttributeMaxDynamicSharedMemorySize, 65536);

  k_conv_bf16<<<2048, 256, 0, stream>>>(in, Ah, MROWS * D_MODEL / 4);
  k_prep_w<<<3072, 256, 0, stream>>>(Wq, Wk, Wv, Wh);
  k_prep_eb<<<2048, 256, 0, stream>>>(pb, eB, N_SEQ * N_SEQ / 4);

  dim3 gp(128, 12);
  k_proj<<<gp, 256, 0, stream>>>(Ah, Wh, bq, bk, bv, sigq, Xf);

  k_main8<<<dim3(512), 512, 65536, stream>>>(eB, Xf, sigq, out);
}